// Round 2
// baseline (1345.808 us; speedup 1.0000x reference)
//
#include <hip/hip_runtime.h>
#include <stdint.h>

// LinearSelfAttention: out = ((phi(xWq) @ (phi(xWk)^T V)) / Z) @ Wo
// B=4 S=8192 H=16 Dh=64 F=128 Dm=1024. All GEMMs bf16-MFMA/fp32-acc.
// R2: phi fused into QKV-GEMM epilogue; ws footprint 520 MiB -> 392 MiB
// (R1 crash attributed to ws overflow past a likely 512 MiB allocation).

#define DEVINL __device__ __forceinline__

typedef float f32x4 __attribute__((ext_vector_type(4)));
typedef __bf16 bf16x8 __attribute__((ext_vector_type(8)));
typedef unsigned short u16;

DEVINL u16 f2bf(float f) {
  union { float f; uint32_t u; } v; v.f = f;
  uint32_t u = v.u;
  u += 0x7fffu + ((u >> 16) & 1u);   // round-to-nearest-even
  return (u16)(u >> 16);
}
DEVINL float bf2f(u16 h) {
  union { uint32_t u; float f; } v; v.u = ((uint32_t)h) << 16;
  return v.f;
}

#define GLOAD16(gp, lp) __builtin_amdgcn_global_load_lds( \
    (const __attribute__((address_space(1))) unsigned int*)(gp), \
    (__attribute__((address_space(3))) unsigned int*)(lp), 16, 0, 0)

// Stage ROWS rows x 128 bytes (row stride in bytes) into LDS [ROWS][128B].
// 256 threads / 4 waves; LDS dest is wave-uniform base (HW adds lane*16).
template <int ROWS>
DEVINL void stage_r128(const uint8_t* g, size_t stride, u16* lds, int wave, int lane) {
#pragma unroll
  for (int j = 0; j < ROWS / 32; ++j) {
    int row = wave * (ROWS / 4) + j * 8 + (lane >> 3);
    GLOAD16(g + (size_t)row * stride + (size_t)(lane & 7) * 16,
            (uint8_t*)lds + (size_t)(wave * (ROWS / 4) + j * 8) * 128);
  }
}

// Stage ROWS rows x 256 bytes into LDS [ROWS][256B].
template <int ROWS>
DEVINL void stage_r256(const uint8_t* g, size_t stride, u16* lds, int wave, int lane) {
#pragma unroll
  for (int j = 0; j < ROWS / 16; ++j) {
    int row = wave * (ROWS / 4) + j * 4 + (lane >> 4);
    GLOAD16(g + (size_t)row * stride + (size_t)(lane & 15) * 16,
            (uint8_t*)lds + (size_t)(wave * (ROWS / 4) + j * 4) * 256);
  }
}

// 128x128 tile, BK=64, 4 waves in 2x2, per-wave 4x4 16x16 frags.
// As/Bs: [128 rows][64 k] bf16. A row = M, B row = N (BT layout).
DEVINL void mma128(const u16* As, const u16* Bs, f32x4 acc[4][4],
                   int wr, int wc, int lane) {
#pragma unroll
  for (int kk = 0; kk < 2; ++kk) {
    const int ko = kk * 32 + (lane >> 4) * 8;
    bf16x8 a[4], b[4];
#pragma unroll
    for (int m = 0; m < 4; ++m)
      a[m] = *(const bf16x8*)&As[(size_t)(wr * 64 + m * 16 + (lane & 15)) * 64 + ko];
#pragma unroll
    for (int n = 0; n < 4; ++n)
      b[n] = *(const bf16x8*)&Bs[(size_t)(wc * 64 + n * 16 + (lane & 15)) * 64 + ko];
#pragma unroll
    for (int m = 0; m < 4; ++m)
#pragma unroll
      for (int n = 0; n < 4; ++n)
        acc[m][n] = __builtin_amdgcn_mfma_f32_16x16x32_bf16(a[m], b[n], acc[m][n], 0, 0, 0);
  }
}

// ---------------- prep kernels ----------------

__global__ __launch_bounds__(256) void cast_x_kernel(
    const float* __restrict__ src, u16* __restrict__ dst, long n4) {
  long i = (long)blockIdx.x * 256 + threadIdx.x;
  const long stride = (long)gridDim.x * 256;
  const float4* s4 = (const float4*)src;
  uint2* d4 = (uint2*)dst;
  for (; i < n4; i += stride) {
    float4 v = s4[i];
    uint2 o;
    o.x = (uint32_t)f2bf(v.x) | ((uint32_t)f2bf(v.y) << 16);
    o.y = (uint32_t)f2bf(v.z) | ((uint32_t)f2bf(v.w) << 16);
    d4[i] = o;
  }
}

// src fp32 [R][C] -> dst bf16 [C][R]
__global__ __launch_bounds__(256) void transpose_cast_kernel(
    const float* __restrict__ src, u16* __restrict__ dst, int R, int C) {
  __shared__ float tile[32 * 33];
  const int ntr = R >> 5;
  const int tr = blockIdx.x % ntr, tc = blockIdx.x / ntr;
  const int tid = threadIdx.x;
  {
    int r = tid >> 3, c4 = (tid & 7) * 4;
    float4 v = *(const float4*)&src[(size_t)(tr * 32 + r) * C + tc * 32 + c4];
    tile[r * 33 + c4 + 0] = v.x;
    tile[r * 33 + c4 + 1] = v.y;
    tile[r * 33 + c4 + 2] = v.z;
    tile[r * 33 + c4 + 3] = v.w;
  }
  __syncthreads();
  {
    int c = tid >> 3, r4 = (tid & 7) * 4;
    uint2 o;
    o.x = (uint32_t)f2bf(tile[(r4 + 0) * 33 + c]) |
          ((uint32_t)f2bf(tile[(r4 + 1) * 33 + c]) << 16);
    o.y = (uint32_t)f2bf(tile[(r4 + 2) * 33 + c]) |
          ((uint32_t)f2bf(tile[(r4 + 3) * 33 + c]) << 16);
    *(uint2*)&dst[(size_t)(tc * 32 + c) * R + tr * 32 + r4] = o;
  }
}

// ---------------- QKV GEMM (N = 3 x 1024) + fused phi ----------------
// tn 0..7 : Q tiles -> phi -> Qp [b,h,s,128]
// tn 8..15: K tiles -> phi -> KpT [b,h,128,s] (transposed via LDS)
// tn 16..23: V tiles -> VhT [b,h,d,s] (transposed via LDS)
__global__ __launch_bounds__(256) void gemm_qkv_phi_kernel(
    const u16* __restrict__ xb, const u16* __restrict__ wT,
    const u16* __restrict__ rfT,
    u16* __restrict__ Qp, u16* __restrict__ KpT, u16* __restrict__ VhT) {
  __shared__ u16 smem[24576];               // 48 KiB
  u16* As = smem;                           // [128][64]
  u16* Bs = smem + 8192;                    // [128][64]
  u16* Rs = smem + 16384;                   // [128 f][64 d] (phi only)
  const int tid = threadIdx.x, lane = tid & 63, wave = tid >> 6;
  const int wr = wave >> 1, wc = wave & 1;
  const int tn = blockIdx.x >> 8, tm = blockIdx.x & 255;
  const int tensor = tn >> 3;

  f32x4 acc[4][4];
#pragma unroll
  for (int m = 0; m < 4; ++m)
#pragma unroll
    for (int n = 0; n < 4; ++n) acc[m][n] = (f32x4){0.f, 0.f, 0.f, 0.f};

  const uint8_t* aB = (const uint8_t*)(xb + (size_t)tm * 128 * 1024);
  const uint8_t* bB = (const uint8_t*)(wT + (size_t)tn * 128 * 1024);
  for (int kt = 0; kt < 16; ++kt) {
    stage_r128<128>(aB + kt * 128, 2048, As, wave, lane);
    stage_r128<128>(bB + kt * 128, 2048, Bs, wave, lane);
    __syncthreads();
    mma128(As, Bs, acc, wr, wc, lane);
    __syncthreads();
  }

  const int b = (tm * 128) >> 13;
  const int sblk = (tm * 128) & 8191;

  if (tensor == 2) {
    // V: transpose full 128x128 tile via LDS, then coalesced 16B rows out.
#pragma unroll
    for (int m = 0; m < 4; ++m) {
      int sl = wr * 64 + m * 16 + (lane >> 4) * 4;
#pragma unroll
      for (int n = 0; n < 4; ++n) {
        int cl = wc * 64 + n * 16 + (lane & 15);
#pragma unroll
        for (int r = 0; r < 4; ++r) smem[cl * 128 + sl + r] = f2bf(acc[m][n][r]);
      }
    }
    __syncthreads();
#pragma unroll
    for (int it = 0; it < 8; ++it) {
      int cl = it * 16 + (tid >> 4);
      int c = (tn & 7) * 128 + cl;
      int h = c >> 6, d = c & 63;
      size_t off = ((size_t)((b * 16 + h) * 64 + d)) * 8192 + sblk + (tid & 15) * 8;
      *(uint4*)&VhT[off] = *(const uint4*)&smem[cl * 128 + (tid & 15) * 8];
    }
    return;
  }

  // ---- Q/K: fused phi ----
  // stage rf fragments (async) while writing the bf16 tile into LDS
  stage_r128<128>((const uint8_t*)rfT, 128, Rs, wave, lane);
  // Qtile: smem[0..16383] as [128 s][128 c] bf16 (overwrites As/Bs)
#pragma unroll
  for (int m = 0; m < 4; ++m) {
    int sl = wr * 64 + m * 16 + (lane >> 4) * 4;
#pragma unroll
    for (int n = 0; n < 4; ++n) {
      int cl = wc * 64 + n * 16 + (lane & 15);
#pragma unroll
      for (int r = 0; r < 4; ++r) smem[(sl + r) * 128 + cl] = f2bf(acc[m][n][r]);
    }
  }
  __syncthreads();   // Qtile written, rf staged (barrier drains vmcnt)

  // per wave: 32 s-rows x 128 f per head, K=64
  f32x4 p[2][2][8];
#pragma unroll
  for (int hh = 0; hh < 2; ++hh)
#pragma unroll
    for (int m = 0; m < 2; ++m)
#pragma unroll
      for (int n = 0; n < 8; ++n) p[hh][m][n] = (f32x4){0.f, 0.f, 0.f, 0.f};

#pragma unroll
  for (int hh = 0; hh < 2; ++hh)
#pragma unroll
    for (int kk = 0; kk < 2; ++kk) {
      const int ko = kk * 32 + (lane >> 4) * 8;
      bf16x8 a[2], bb[8];
#pragma unroll
      for (int m = 0; m < 2; ++m)
        a[m] = *(const bf16x8*)&smem[(size_t)(wave * 32 + m * 16 + (lane & 15)) * 128 +
                                     hh * 64 + ko];
#pragma unroll
      for (int n = 0; n < 8; ++n)
        bb[n] = *(const bf16x8*)&Rs[(size_t)(n * 16 + (lane & 15)) * 64 + ko];
#pragma unroll
      for (int m = 0; m < 2; ++m)
#pragma unroll
        for (int n = 0; n < 8; ++n)
          p[hh][m][n] = __builtin_amdgcn_mfma_f32_16x16x32_bf16(a[m], bb[n], p[hh][m][n], 0, 0, 0);
    }

  const float SC = 0.088388347648318447f;  // 128^-0.5
  if (tensor == 0) {
    // Q: direct scattered store to Qp[b,h,s,128]
#pragma unroll
    for (int hh = 0; hh < 2; ++hh) {
      const int h = (tn & 7) * 2 + hh;
      const size_t base_bh = (size_t)(b * 16 + h) * 8192;
#pragma unroll
      for (int m = 0; m < 2; ++m)
#pragma unroll
        for (int n = 0; n < 8; ++n) {
          int f = n * 16 + (lane & 15);
          int s0 = sblk + wave * 32 + m * 16 + (lane >> 4) * 4;
#pragma unroll
          for (int r = 0; r < 4; ++r) {
            float v = ((n < 4) ? cosf(p[hh][m][n][r]) : sinf(p[hh][m][n][r])) * SC;
            Qp[(base_bh + s0 + r) * 128 + f] = f2bf(v);
          }
        }
    }
  } else {
    // K: per head, transpose phi via LDS then coalesced store to KpT[b,h,f,s]
#pragma unroll
    for (int hh = 0; hh < 2; ++hh) {
      __syncthreads();   // done reading Qtile (hh=0) / prior stores (hh=1)
#pragma unroll
      for (int m = 0; m < 2; ++m)
#pragma unroll
        for (int n = 0; n < 8; ++n) {
          int f = n * 16 + (lane & 15);
          int sl = wave * 32 + m * 16 + (lane >> 4) * 4;
#pragma unroll
          for (int r = 0; r < 4; ++r) {
            float v = ((n < 4) ? cosf(p[hh][m][n][r]) : sinf(p[hh][m][n][r])) * SC;
            smem[f * 128 + sl + r] = f2bf(v);
          }
        }
      __syncthreads();
      const int h = (tn & 7) * 2 + hh;
#pragma unroll
      for (int it = 0; it < 8; ++it) {
        int f = it * 16 + (tid >> 4);
        *(uint4*)&KpT[((size_t)(b * 16 + h) * 128 + f) * 8192 + sblk + (tid & 15) * 8] =
            *(const uint4*)&smem[f * 128 + (tid & 15) * 8];
      }
    }
  }
}

// ---------------- KV = Kp^T V + Ksum, partial over s-chunks ----------------
// partial[blk][f 128][65]: cols 0..63 = KV[f][d], col 64 = Ksum[f]
__global__ __launch_bounds__(256) void kv_partial_kernel(
    const u16* __restrict__ KpT, const u16* __restrict__ VhT,
    float* __restrict__ partial) {
  __shared__ u16 smem[12288];
  __shared__ float ksmem[256];
  u16* As = smem;        // [128 f][64 s]
  u16* Bs = smem + 8192; // [64 d][64 s]
  const int tid = threadIdx.x, lane = tid & 63, wave = tid >> 6;
  const int bh = blockIdx.x >> 3, ch = blockIdx.x & 7;
  const uint8_t* aB = (const uint8_t*)(KpT + (size_t)bh * 128 * 8192 + ch * 1024);
  const uint8_t* bB = (const uint8_t*)(VhT + (size_t)bh * 64 * 8192 + ch * 1024);

  f32x4 acc[2][4];
#pragma unroll
  for (int m = 0; m < 2; ++m)
#pragma unroll
    for (int n = 0; n < 4; ++n) acc[m][n] = (f32x4){0.f, 0.f, 0.f, 0.f};
  float ks = 0.f;
  const int fK = tid >> 1, sO = (tid & 1) * 32;

  for (int t = 0; t < 16; ++t) {
    stage_r128<128>(aB + t * 128, 16384, As, wave, lane);
    stage_r128<64>(bB + t * 128, 16384, Bs, wave, lane);
    __syncthreads();
#pragma unroll
    for (int i = 0; i < 4; ++i) {
      uint4 v = *(const uint4*)&As[fK * 64 + sO + i * 8];
      ks += bf2f((u16)(v.x & 0xffff)) + bf2f((u16)(v.x >> 16));
      ks += bf2f((u16)(v.y & 0xffff)) + bf2f((u16)(v.y >> 16));
      ks += bf2f((u16)(v.z & 0xffff)) + bf2f((u16)(v.z >> 16));
      ks += bf2f((u16)(v.w & 0xffff)) + bf2f((u16)(v.w >> 16));
    }
#pragma unroll
    for (int kk = 0; kk < 2; ++kk) {
      const int ko = kk * 32 + (lane >> 4) * 8;
      bf16x8 a[2], bb[4];
#pragma unroll
      for (int m = 0; m < 2; ++m)
        a[m] = *(const bf16x8*)&As[(size_t)(wave * 32 + m * 16 + (lane & 15)) * 64 + ko];
#pragma unroll
      for (int n = 0; n < 4; ++n)
        bb[n] = *(const bf16x8*)&Bs[(size_t)(n * 16 + (lane & 15)) * 64 + ko];
#pragma unroll
      for (int m = 0; m < 2; ++m)
#pragma unroll
        for (int n = 0; n < 4; ++n)
          acc[m][n] = __builtin_amdgcn_mfma_f32_16x16x32_bf16(a[m], bb[n], acc[m][n], 0, 0, 0);
    }
    __syncthreads();
  }

  float* pb = partial + (size_t)blockIdx.x * (128 * 65);
#pragma unroll
  for (int m = 0; m < 2; ++m)
#pragma unroll
    for (int n = 0; n < 4; ++n) {
      int d = n * 16 + (lane & 15);
#pragma unroll
      for (int r = 0; r < 4; ++r) {
        int f = wave * 32 + m * 16 + (lane >> 4) * 4 + r;
        pb[f * 65 + d] = acc[m][n][r];
      }
    }
  ksmem[tid] = ks;
  __syncthreads();
  if (tid < 128) pb[tid * 65 + 64] = ksmem[2 * tid] + ksmem[2 * tid + 1];
}

// reduce partials -> KVT [bh][80 rows][128 f] bf16 (row 64 = Ksum, 65..79 = 0)
__global__ __launch_bounds__(256) void kv_reduce_kernel(
    const float* __restrict__ partial, u16* __restrict__ KVT) {
  const int bh = blockIdx.x, tid = threadIdx.x;
  for (int e = tid; e < 8320; e += 256) {
    float s = 0.f;
#pragma unroll
    for (int c = 0; c < 8; ++c) s += partial[(size_t)(bh * 8 + c) * 8320 + e];
    int f = e / 65, col = e % 65;
    KVT[((size_t)bh * 80 + col) * 128 + f] = f2bf(s);
  }
  for (int i = tid; i < 15 * 128; i += 256)
    KVT[((size_t)bh * 80 + 65) * 128 + i] = 0;
}

// ---------------- QKV = Qp @ KV, Z via 5th N-frag, divide -> A bf16 ----------------
__global__ __launch_bounds__(256) void qkv_div_kernel(
    const u16* __restrict__ Qp, const u16* __restrict__ KVT, u16* __restrict__ A) {
  __shared__ u16 smem[26624];
  u16* Qs = smem;          // [128 s][128 f]
  u16* Ks = smem + 16384;  // [80 rows][128 f]
  const int tid = threadIdx.x, lane = tid & 63, wave = tid >> 6;
  const int bh = blockIdx.x >> 6, st = blockIdx.x & 63;

  stage_r256<128>((const uint8_t*)(Qp + ((size_t)bh * 8192 + st * 128) * 128), 256,
                  Qs, wave, lane);
  stage_r256<80>((const uint8_t*)(KVT + (size_t)bh * 80 * 128), 256, Ks, wave, lane);
  __syncthreads();

  f32x4 acc[2][5];
#pragma unroll
  for (int m = 0; m < 2; ++m)
#pragma unroll
    for (int n = 0; n < 5; ++n) acc[m][n] = (f32x4){0.f, 0.f, 0.f, 0.f};

#pragma unroll
  for (int kk = 0; kk < 4; ++kk) {
    const int ko = kk * 32 + (lane >> 4) * 8;
    bf16x8 a[2], bb[5];
#pragma unroll
    for (int m = 0; m < 2; ++m)
      a[m] = *(const bf16x8*)&Qs[(size_t)(wave * 32 + m * 16 + (lane & 15)) * 128 + ko];
#pragma unroll
    for (int n = 0; n < 5; ++n)
      bb[n] = *(const bf16x8*)&Ks[(size_t)(n * 16 + (lane & 15)) * 128 + ko];
#pragma unroll
    for (int m = 0; m < 2; ++m)
#pragma unroll
      for (int n = 0; n < 5; ++n)
        acc[m][n] = __builtin_amdgcn_mfma_f32_16x16x32_bf16(a[m], bb[n], acc[m][n], 0, 0, 0);
  }

  const int b_ = bh >> 4, h = bh & 15;
#pragma unroll
  for (int m = 0; m < 2; ++m) {
#pragma unroll
    for (int r = 0; r < 4; ++r) {
      float z = fmaxf(__shfl(acc[m][4][r], lane & 48), 1e-6f);
      int srow = st * 128 + wave * 32 + m * 16 + (lane >> 4) * 4 + r;
      size_t rowb = ((size_t)b_ * 8192 + srow) * 1024 + h * 64;
#pragma unroll
      for (int n = 0; n < 4; ++n)
        A[rowb + n * 16 + (lane & 15)] = f2bf(acc[m][n][r] / z);
    }
  }
}

// ---------------- out = A @ Wo (fp32 out) ----------------
__global__ __launch_bounds__(256) void gemm_out_kernel(
    const u16* __restrict__ A, const u16* __restrict__ WoT, float* __restrict__ out) {
  __shared__ u16 smem[16384];
  u16* As = smem;
  u16* Bs = smem + 8192;
  const int tid = threadIdx.x, lane = tid & 63, wave = tid >> 6;
  const int wr = wave >> 1, wc = wave & 1;
  const int tn = blockIdx.x >> 8, tm = blockIdx.x & 255;

  f32x4 acc[4][4];
#pragma unroll
  for (int m = 0; m < 4; ++m)
#pragma unroll
    for (int n = 0; n < 4; ++n) acc[m][n] = (f32x4){0.f, 0.f, 0.f, 0.f};

  const uint8_t* aB = (const uint8_t*)(A + (size_t)tm * 128 * 1024);
  const uint8_t* bB = (const uint8_t*)(WoT + (size_t)tn * 128 * 1024);
  for (int kt = 0; kt < 16; ++kt) {
    stage_r128<128>(aB + kt * 128, 2048, As, wave, lane);
    stage_r128<128>(bB + kt * 128, 2048, Bs, wave, lane);
    __syncthreads();
    mma128(As, Bs, acc, wr, wc, lane);
    __syncthreads();
  }

  const int rowbase = tm * 128 + wr * 64;
  const int colbase = tn * 128 + wc * 64;
#pragma unroll
  for (int m = 0; m < 4; ++m)
#pragma unroll
    for (int n = 0; n < 4; ++n) {
      int col = colbase + n * 16 + (lane & 15);
      int row = rowbase + m * 16 + (lane >> 4) * 4;
#pragma unroll
      for (int r = 0; r < 4; ++r)
        out[(size_t)(row + r) * 1024 + col] = acc[m][n][r];
    }
}

// ---------------- host ----------------

extern "C" void kernel_launch(void* const* d_in, const int* in_sizes, int n_in,
                              void* d_out, int out_size, void* d_ws, size_t ws_size,
                              hipStream_t stream) {
  const float* x  = (const float*)d_in[0];
  const float* Wq = (const float*)d_in[1];
  const float* Wk = (const float*)d_in[2];
  const float* Wv = (const float*)d_in[3];
  const float* Wo = (const float*)d_in[4];
  const float* rf = (const float*)d_in[5];
  float* out = (float*)d_out;

  // ws layout (u16 elements), total 411,058,176 bytes (392.05 MiB):
  //   [0,        33554432): xb          -> partial (f32, 17 MiB) -> A
  //   [33554432, 100663296): Qp
  //   [100663296,167772160): KpT
  //   [167772160,201326592): VhT
  //   [201326592,204472320): wqkvT      -> KVT (after gemm)
  //   [204472320,205520896): woT
  //   [205520896,205529088): rfT
  if (ws_size < (size_t)411058176) return;   // fail cleanly, don't fault

  u16* ws = (u16*)d_ws;
  u16* xb    = ws;
  u16* Qp    = ws + 33554432UL;
  u16* KpT   = ws + 100663296UL;
  u16* VhT   = ws + 167772160UL;
  u16* wqkvT = ws + 201326592UL;
  u16* woT   = ws + 204472320UL;
  u16* rfT   = ws + 205520896UL;
  float* partial = (float*)xb;          // [512][128][65] f32, alias xb (dead)
  u16* KVT   = wqkvT;                   // [64][80][128] bf16, alias wqkvT (dead)
  u16* Abuf  = xb;                      // [32768][1024] bf16, alias xb

  cast_x_kernel<<<4096, 256, 0, stream>>>(x, xb, 8388608L);
  transpose_cast_kernel<<<1024, 256, 0, stream>>>(Wq, wqkvT,            1024, 1024);
  transpose_cast_kernel<<<1024, 256, 0, stream>>>(Wk, wqkvT + 1048576,  1024, 1024);
  transpose_cast_kernel<<<1024, 256, 0, stream>>>(Wv, wqkvT + 2097152,  1024, 1024);
  transpose_cast_kernel<<<1024, 256, 0, stream>>>(Wo, woT,              1024, 1024);
  transpose_cast_kernel<<<8,    256, 0, stream>>>(rf, rfT,              64,   128);

  gemm_qkv_phi_kernel<<<6144, 256, 0, stream>>>(xb, wqkvT, rfT, Qp, KpT, VhT);
  kv_partial_kernel<<<512, 256, 0, stream>>>(KpT, VhT, partial);
  kv_reduce_kernel<<<64, 256, 0, stream>>>(partial, KVT);
  qkv_div_kernel<<<4096, 256, 0, stream>>>(Qp, KVT, Abuf);
  gemm_out_kernel<<<2048, 256, 0, stream>>>(Abuf, woT, out);
}

// Round 3
// 874.484 us; speedup vs baseline: 1.5390x; 1.5390x over previous
//
#include <hip/hip_runtime.h>
#include <stdint.h>

// LinearSelfAttention: out = ((phi(xWq) @ (phi(xWk)^T V)) / Z) @ Wo
// B=4 S=8192 H=16 Dh=64 F=128 Dm=1024. All GEMMs bf16-MFMA/fp32-acc.
// R3: epilogue bank-conflict fixes (pad 136/72), Q store via LDS (coalesced),
//     fast __sinf/__cosf, tm-major block order for L2 reuse.

#define DEVINL __device__ __forceinline__

typedef float f32x4 __attribute__((ext_vector_type(4)));
typedef __bf16 bf16x8 __attribute__((ext_vector_type(8)));
typedef unsigned short u16;

#define TSTR 136   // epilogue tile row stride (u16): 272B, 16B-aligned, 4 mod 32 words
#define RSTR 72    // rf row stride (u16): 144B, 16B-aligned

DEVINL u16 f2bf(float f) {
  union { float f; uint32_t u; } v; v.f = f;
  uint32_t u = v.u;
  u += 0x7fffu + ((u >> 16) & 1u);   // round-to-nearest-even
  return (u16)(u >> 16);
}
DEVINL float bf2f(u16 h) {
  union { uint32_t u; float f; } v; v.u = ((uint32_t)h) << 16;
  return v.f;
}

#define GLOAD16(gp, lp) __builtin_amdgcn_global_load_lds( \
    (const __attribute__((address_space(1))) unsigned int*)(gp), \
    (__attribute__((address_space(3))) unsigned int*)(lp), 16, 0, 0)

// Stage ROWS rows x 128 bytes (row stride in bytes) into LDS [ROWS][128B].
template <int ROWS>
DEVINL void stage_r128(const uint8_t* g, size_t stride, u16* lds, int wave, int lane) {
#pragma unroll
  for (int j = 0; j < ROWS / 32; ++j) {
    int row = wave * (ROWS / 4) + j * 8 + (lane >> 3);
    GLOAD16(g + (size_t)row * stride + (size_t)(lane & 7) * 16,
            (uint8_t*)lds + (size_t)(wave * (ROWS / 4) + j * 8) * 128);
  }
}

// Stage ROWS rows x 256 bytes into LDS [ROWS][256B].
template <int ROWS>
DEVINL void stage_r256(const uint8_t* g, size_t stride, u16* lds, int wave, int lane) {
#pragma unroll
  for (int j = 0; j < ROWS / 16; ++j) {
    int row = wave * (ROWS / 4) + j * 4 + (lane >> 4);
    GLOAD16(g + (size_t)row * stride + (size_t)(lane & 15) * 16,
            (uint8_t*)lds + (size_t)(wave * (ROWS / 4) + j * 4) * 256);
  }
}

// 128x128 tile, BK=64, 4 waves in 2x2, per-wave 4x4 16x16 frags.
DEVINL void mma128(const u16* As, const u16* Bs, f32x4 acc[4][4],
                   int wr, int wc, int lane) {
#pragma unroll
  for (int kk = 0; kk < 2; ++kk) {
    const int ko = kk * 32 + (lane >> 4) * 8;
    bf16x8 a[4], b[4];
#pragma unroll
    for (int m = 0; m < 4; ++m)
      a[m] = *(const bf16x8*)&As[(size_t)(wr * 64 + m * 16 + (lane & 15)) * 64 + ko];
#pragma unroll
    for (int n = 0; n < 4; ++n)
      b[n] = *(const bf16x8*)&Bs[(size_t)(wc * 64 + n * 16 + (lane & 15)) * 64 + ko];
#pragma unroll
    for (int m = 0; m < 4; ++m)
#pragma unroll
      for (int n = 0; n < 4; ++n)
        acc[m][n] = __builtin_amdgcn_mfma_f32_16x16x32_bf16(a[m], b[n], acc[m][n], 0, 0, 0);
  }
}

// ---------------- prep kernels ----------------

__global__ __launch_bounds__(256) void cast_x_kernel(
    const float* __restrict__ src, u16* __restrict__ dst, long n4) {
  long i = (long)blockIdx.x * 256 + threadIdx.x;
  const long stride = (long)gridDim.x * 256;
  const float4* s4 = (const float4*)src;
  uint2* d4 = (uint2*)dst;
  for (; i < n4; i += stride) {
    float4 v = s4[i];
    uint2 o;
    o.x = (uint32_t)f2bf(v.x) | ((uint32_t)f2bf(v.y) << 16);
    o.y = (uint32_t)f2bf(v.z) | ((uint32_t)f2bf(v.w) << 16);
    d4[i] = o;
  }
}

// src fp32 [R][C] -> dst bf16 [C][R]
__global__ __launch_bounds__(256) void transpose_cast_kernel(
    const float* __restrict__ src, u16* __restrict__ dst, int R, int C) {
  __shared__ float tile[32 * 33];
  const int ntr = R >> 5;
  const int tr = blockIdx.x % ntr, tc = blockIdx.x / ntr;
  const int tid = threadIdx.x;
  {
    int r = tid >> 3, c4 = (tid & 7) * 4;
    float4 v = *(const float4*)&src[(size_t)(tr * 32 + r) * C + tc * 32 + c4];
    tile[r * 33 + c4 + 0] = v.x;
    tile[r * 33 + c4 + 1] = v.y;
    tile[r * 33 + c4 + 2] = v.z;
    tile[r * 33 + c4 + 3] = v.w;
  }
  __syncthreads();
  {
    int c = tid >> 3, r4 = (tid & 7) * 4;
    uint2 o;
    o.x = (uint32_t)f2bf(tile[(r4 + 0) * 33 + c]) |
          ((uint32_t)f2bf(tile[(r4 + 1) * 33 + c]) << 16);
    o.y = (uint32_t)f2bf(tile[(r4 + 2) * 33 + c]) |
          ((uint32_t)f2bf(tile[(r4 + 3) * 33 + c]) << 16);
    *(uint2*)&dst[(size_t)(tc * 32 + c) * R + tr * 32 + r4] = o;
  }
}

// ---------------- QKV GEMM (N = 3 x 1024) + fused phi ----------------
// tn 0..7 : Q -> phi -> Qp [b,h,s,128] (LDS-coalesced)
// tn 8..15: K -> phi -> KpT [b,h,128,s] (LDS transpose)
// tn 16..23: V -> VhT [b,h,d,s] (LDS transpose)
__global__ __launch_bounds__(256) void gemm_qkv_phi_kernel(
    const u16* __restrict__ xb, const u16* __restrict__ wT,
    const u16* __restrict__ rfT,
    u16* __restrict__ Qp, u16* __restrict__ KpT, u16* __restrict__ VhT) {
  __shared__ u16 smem[26624];               // 52 KiB: TILE[128*136] + Rs[128*72]
  u16* As = smem;                           // [128][64] linear (global_load_lds)
  u16* Bs = smem + 8192;                    // [128][64] linear
  u16* Rs = smem + 17408;                   // [128 f][72] padded
  const int tid = threadIdx.x, lane = tid & 63, wave = tid >> 6;
  const int wr = wave >> 1, wc = wave & 1;
  const int tn = blockIdx.x % 24, tm = blockIdx.x / 24;  // tm-major: L2 A-reuse
  const int tensor = tn >> 3;

  // stage rf once (padded rows -> conflict-free phi B-frag reads)
  if (tensor < 2) {
#pragma unroll
    for (int p = 0; p < 4; ++p) {
      int idx = p * 256 + tid;
      int f = idx >> 3, c = idx & 7;
      *(uint4*)&Rs[f * RSTR + c * 8] = *(const uint4*)&rfT[f * 64 + c * 8];
    }
  }

  f32x4 acc[4][4];
#pragma unroll
  for (int m = 0; m < 4; ++m)
#pragma unroll
    for (int n = 0; n < 4; ++n) acc[m][n] = (f32x4){0.f, 0.f, 0.f, 0.f};

  const uint8_t* aB = (const uint8_t*)(xb + (size_t)tm * 128 * 1024);
  const uint8_t* bB = (const uint8_t*)(wT + (size_t)tn * 128 * 1024);
  for (int kt = 0; kt < 16; ++kt) {
    stage_r128<128>(aB + kt * 128, 2048, As, wave, lane);
    stage_r128<128>(bB + kt * 128, 2048, Bs, wave, lane);
    __syncthreads();
    mma128(As, Bs, acc, wr, wc, lane);
    __syncthreads();
  }

  const int b = (tm * 128) >> 13;
  const int sblk = (tm * 128) & 8191;

  if (tensor == 2) {
    // V: transpose 128x128 tile via padded LDS, coalesced 16B rows out.
#pragma unroll
    for (int m = 0; m < 4; ++m) {
      int sl = wr * 64 + m * 16 + (lane >> 4) * 4;
#pragma unroll
      for (int n = 0; n < 4; ++n) {
        int cl = wc * 64 + n * 16 + (lane & 15);
#pragma unroll
        for (int r = 0; r < 4; ++r) smem[cl * TSTR + sl + r] = f2bf(acc[m][n][r]);
      }
    }
    __syncthreads();
#pragma unroll
    for (int it = 0; it < 8; ++it) {
      int cl = it * 16 + (tid >> 4);
      int c = (tn & 7) * 128 + cl;
      int h = c >> 6, d = c & 63;
      size_t off = ((size_t)((b * 16 + h) * 64 + d)) * 8192 + sblk + (tid & 15) * 8;
      *(uint4*)&VhT[off] = *(const uint4*)&smem[cl * TSTR + (tid & 15) * 8];
    }
    return;
  }

  // ---- Q/K: fused phi ----
  // write bf16 GEMM tile into TILE as [128 s][TSTR]
#pragma unroll
  for (int m = 0; m < 4; ++m) {
    int sl = wr * 64 + m * 16 + (lane >> 4) * 4;
#pragma unroll
    for (int n = 0; n < 4; ++n) {
      int cl = wc * 64 + n * 16 + (lane & 15);
#pragma unroll
      for (int r = 0; r < 4; ++r) smem[(sl + r) * TSTR + cl] = f2bf(acc[m][n][r]);
    }
  }
  __syncthreads();

  // per wave: 32 s-rows x 128 f per head, K=64
  f32x4 p[2][2][8];
#pragma unroll
  for (int hh = 0; hh < 2; ++hh)
#pragma unroll
    for (int m = 0; m < 2; ++m)
#pragma unroll
      for (int n = 0; n < 8; ++n) p[hh][m][n] = (f32x4){0.f, 0.f, 0.f, 0.f};

#pragma unroll
  for (int hh = 0; hh < 2; ++hh)
#pragma unroll
    for (int kk = 0; kk < 2; ++kk) {
      const int ko = kk * 32 + (lane >> 4) * 8;
      bf16x8 a[2], bb[8];
#pragma unroll
      for (int m = 0; m < 2; ++m)
        a[m] = *(const bf16x8*)&smem[(size_t)(wave * 32 + m * 16 + (lane & 15)) * TSTR +
                                     hh * 64 + ko];
#pragma unroll
      for (int n = 0; n < 8; ++n)
        bb[n] = *(const bf16x8*)&Rs[(size_t)(n * 16 + (lane & 15)) * RSTR + ko];
#pragma unroll
      for (int m = 0; m < 2; ++m)
#pragma unroll
        for (int n = 0; n < 8; ++n)
          p[hh][m][n] = __builtin_amdgcn_mfma_f32_16x16x32_bf16(a[m], bb[n], p[hh][m][n], 0, 0, 0);
    }

  const float SC = 0.088388347648318447f;  // 128^-0.5
#pragma unroll
  for (int hh = 0; hh < 2; ++hh) {
    const int h = (tn & 7) * 2 + hh;
    __syncthreads();   // all phi reads of TILE done / prior stores done
    if (tensor == 0) {
      // Q: phi values into TILE [128 s][TSTR], then coalesced row stores
#pragma unroll
      for (int m = 0; m < 2; ++m)
#pragma unroll
        for (int n = 0; n < 8; ++n) {
          int f = n * 16 + (lane & 15);
          int sl = wave * 32 + m * 16 + (lane >> 4) * 4;
#pragma unroll
          for (int r = 0; r < 4; ++r) {
            float v = ((n < 4) ? __cosf(p[hh][m][n][r]) : __sinf(p[hh][m][n][r])) * SC;
            smem[(sl + r) * TSTR + f] = f2bf(v);
          }
        }
      __syncthreads();
      const size_t base_bh = (size_t)(b * 16 + h) * 8192;
#pragma unroll
      for (int it = 0; it < 8; ++it) {
        int s = it * 16 + (tid >> 4);
        *(uint4*)&Qp[(base_bh + sblk + s) * 128 + (tid & 15) * 8] =
            *(const uint4*)&smem[s * TSTR + (tid & 15) * 8];
      }
    } else {
      // K: phi values transposed into TILE [128 f][TSTR], coalesced s-rows out
#pragma unroll
      for (int m = 0; m < 2; ++m)
#pragma unroll
        for (int n = 0; n < 8; ++n) {
          int f = n * 16 + (lane & 15);
          int sl = wave * 32 + m * 16 + (lane >> 4) * 4;
#pragma unroll
          for (int r = 0; r < 4; ++r) {
            float v = ((n < 4) ? __cosf(p[hh][m][n][r]) : __sinf(p[hh][m][n][r])) * SC;
            smem[f * TSTR + sl + r] = f2bf(v);
          }
        }
      __syncthreads();
#pragma unroll
      for (int it = 0; it < 8; ++it) {
        int f = it * 16 + (tid >> 4);
        *(uint4*)&KpT[((size_t)(b * 16 + h) * 128 + f) * 8192 + sblk + (tid & 15) * 8] =
            *(const uint4*)&smem[f * TSTR + (tid & 15) * 8];
      }
    }
  }
}

// ---------------- KV = Kp^T V + Ksum, partial over s-chunks ----------------
__global__ __launch_bounds__(256) void kv_partial_kernel(
    const u16* __restrict__ KpT, const u16* __restrict__ VhT,
    float* __restrict__ partial) {
  __shared__ u16 smem[12288];
  __shared__ float ksmem[256];
  u16* As = smem;        // [128 f][64 s]
  u16* Bs = smem + 8192; // [64 d][64 s]
  const int tid = threadIdx.x, lane = tid & 63, wave = tid >> 6;
  const int bh = blockIdx.x >> 3, ch = blockIdx.x & 7;
  const uint8_t* aB = (const uint8_t*)(KpT + (size_t)bh * 128 * 8192 + ch * 1024);
  const uint8_t* bB = (const uint8_t*)(VhT + (size_t)bh * 64 * 8192 + ch * 1024);

  f32x4 acc[2][4];
#pragma unroll
  for (int m = 0; m < 2; ++m)
#pragma unroll
    for (int n = 0; n < 4; ++n) acc[m][n] = (f32x4){0.f, 0.f, 0.f, 0.f};
  float ks = 0.f;
  const int fK = tid >> 1, sO = (tid & 1) * 32;

  for (int t = 0; t < 16; ++t) {
    stage_r128<128>(aB + t * 128, 16384, As, wave, lane);
    stage_r128<64>(bB + t * 128, 16384, Bs, wave, lane);
    __syncthreads();
#pragma unroll
    for (int i = 0; i < 4; ++i) {
      uint4 v = *(const uint4*)&As[fK * 64 + sO + i * 8];
      ks += bf2f((u16)(v.x & 0xffff)) + bf2f((u16)(v.x >> 16));
      ks += bf2f((u16)(v.y & 0xffff)) + bf2f((u16)(v.y >> 16));
      ks += bf2f((u16)(v.z & 0xffff)) + bf2f((u16)(v.z >> 16));
      ks += bf2f((u16)(v.w & 0xffff)) + bf2f((u16)(v.w >> 16));
    }
#pragma unroll
    for (int kk = 0; kk < 2; ++kk) {
      const int ko = kk * 32 + (lane >> 4) * 8;
      bf16x8 a[2], bb[4];
#pragma unroll
      for (int m = 0; m < 2; ++m)
        a[m] = *(const bf16x8*)&As[(size_t)(wave * 32 + m * 16 + (lane & 15)) * 64 + ko];
#pragma unroll
      for (int n = 0; n < 4; ++n)
        bb[n] = *(const bf16x8*)&Bs[(size_t)(n * 16 + (lane & 15)) * 64 + ko];
#pragma unroll
      for (int m = 0; m < 2; ++m)
#pragma unroll
        for (int n = 0; n < 4; ++n)
          acc[m][n] = __builtin_amdgcn_mfma_f32_16x16x32_bf16(a[m], bb[n], acc[m][n], 0, 0, 0);
    }
    __syncthreads();
  }

  float* pb = partial + (size_t)blockIdx.x * (128 * 65);
#pragma unroll
  for (int m = 0; m < 2; ++m)
#pragma unroll
    for (int n = 0; n < 4; ++n) {
      int d = n * 16 + (lane & 15);
#pragma unroll
      for (int r = 0; r < 4; ++r) {
        int f = wave * 32 + m * 16 + (lane >> 4) * 4 + r;
        pb[f * 65 + d] = acc[m][n][r];
      }
    }
  ksmem[tid] = ks;
  __syncthreads();
  if (tid < 128) pb[tid * 65 + 64] = ksmem[2 * tid] + ksmem[2 * tid + 1];
}

// reduce partials -> KVT [bh][80 rows][128 f] bf16 (row 64 = Ksum, 65..79 = 0)
__global__ __launch_bounds__(256) void kv_reduce_kernel(
    const float* __restrict__ partial, u16* __restrict__ KVT) {
  const int bh = blockIdx.x, tid = threadIdx.x;
  for (int e = tid; e < 8320; e += 256) {
    float s = 0.f;
#pragma unroll
    for (int c = 0; c < 8; ++c) s += partial[(size_t)(bh * 8 + c) * 8320 + e];
    int f = e / 65, col = e % 65;
    KVT[((size_t)bh * 80 + col) * 128 + f] = f2bf(s);
  }
  for (int i = tid; i < 15 * 128; i += 256)
    KVT[((size_t)bh * 80 + 65) * 128 + i] = 0;
}

// ---------------- QKV = Qp @ KV, Z via 5th N-frag, divide -> A bf16 ----------------
__global__ __launch_bounds__(256) void qkv_div_kernel(
    const u16* __restrict__ Qp, const u16* __restrict__ KVT, u16* __restrict__ A) {
  __shared__ u16 smem[26624];
  u16* Qs = smem;          // [128 s][128 f]
  u16* Ks = smem + 16384;  // [80 rows][128 f]
  const int tid = threadIdx.x, lane = tid & 63, wave = tid >> 6;
  const int bh = blockIdx.x >> 6, st = blockIdx.x & 63;

  stage_r256<128>((const uint8_t*)(Qp + ((size_t)bh * 8192 + st * 128) * 128), 256,
                  Qs, wave, lane);
  stage_r256<80>((const uint8_t*)(KVT + (size_t)bh * 80 * 128), 256, Ks, wave, lane);
  __syncthreads();

  f32x4 acc[2][5];
#pragma unroll
  for (int m = 0; m < 2; ++m)
#pragma unroll
    for (int n = 0; n < 5; ++n) acc[m][n] = (f32x4){0.f, 0.f, 0.f, 0.f};

#pragma unroll
  for (int kk = 0; kk < 4; ++kk) {
    const int ko = kk * 32 + (lane >> 4) * 8;
    bf16x8 a[2], bb[5];
#pragma unroll
    for (int m = 0; m < 2; ++m)
      a[m] = *(const bf16x8*)&Qs[(size_t)(wave * 32 + m * 16 + (lane & 15)) * 128 + ko];
#pragma unroll
    for (int n = 0; n < 5; ++n)
      bb[n] = *(const bf16x8*)&Ks[(size_t)(n * 16 + (lane & 15)) * 128 + ko];
#pragma unroll
    for (int m = 0; m < 2; ++m)
#pragma unroll
      for (int n = 0; n < 5; ++n)
        acc[m][n] = __builtin_amdgcn_mfma_f32_16x16x32_bf16(a[m], bb[n], acc[m][n], 0, 0, 0);
  }

  const int b_ = bh >> 4, h = bh & 15;
#pragma unroll
  for (int m = 0; m < 2; ++m) {
#pragma unroll
    for (int r = 0; r < 4; ++r) {
      float z = fmaxf(__shfl(acc[m][4][r], lane & 48), 1e-6f);
      int srow = st * 128 + wave * 32 + m * 16 + (lane >> 4) * 4 + r;
      size_t rowb = ((size_t)b_ * 8192 + srow) * 1024 + h * 64;
#pragma unroll
      for (int n = 0; n < 4; ++n)
        A[rowb + n * 16 + (lane & 15)] = f2bf(acc[m][n][r] / z);
    }
  }
}

// ---------------- out = A @ Wo (fp32 out) ----------------
__global__ __launch_bounds__(256) void gemm_out_kernel(
    const u16* __restrict__ A, const u16* __restrict__ WoT, float* __restrict__ out) {
  __shared__ u16 smem[16384];
  u16* As = smem;
  u16* Bs = smem + 8192;
  const int tid = threadIdx.x, lane = tid & 63, wave = tid >> 6;
  const int wr = wave >> 1, wc = wave & 1;
  const int tn = blockIdx.x & 7, tm = blockIdx.x >> 3;  // tm-major

  f32x4 acc[4][4];
#pragma unroll
  for (int m = 0; m < 4; ++m)
#pragma unroll
    for (int n = 0; n < 4; ++n) acc[m][n] = (f32x4){0.f, 0.f, 0.f, 0.f};

  const uint8_t* aB = (const uint8_t*)(A + (size_t)tm * 128 * 1024);
  const uint8_t* bB = (const uint8_t*)(WoT + (size_t)tn * 128 * 1024);
  for (int kt = 0; kt < 16; ++kt) {
    stage_r128<128>(aB + kt * 128, 2048, As, wave, lane);
    stage_r128<128>(bB + kt * 128, 2048, Bs, wave, lane);
    __syncthreads();
    mma128(As, Bs, acc, wr, wc, lane);
    __syncthreads();
  }

  const int rowbase = tm * 128 + wr * 64;
  const int colbase = tn * 128 + wc * 64;
#pragma unroll
  for (int m = 0; m < 4; ++m)
#pragma unroll
    for (int n = 0; n < 4; ++n) {
      int col = colbase + n * 16 + (lane & 15);
      int row = rowbase + m * 16 + (lane >> 4) * 4;
#pragma unroll
      for (int r = 0; r < 4; ++r)
        out[(size_t)(row + r) * 1024 + col] = acc[m][n][r];
    }
}

// ---------------- host ----------------

extern "C" void kernel_launch(void* const* d_in, const int* in_sizes, int n_in,
                              void* d_out, int out_size, void* d_ws, size_t ws_size,
                              hipStream_t stream) {
  const float* x  = (const float*)d_in[0];
  const float* Wq = (const float*)d_in[1];
  const float* Wk = (const float*)d_in[2];
  const float* Wv = (const float*)d_in[3];
  const float* Wo = (const float*)d_in[4];
  const float* rf = (const float*)d_in[5];
  float* out = (float*)d_out;

  if (ws_size < (size_t)411058176) return;   // fail cleanly, don't fault

  u16* ws = (u16*)d_ws;
  u16* xb    = ws;
  u16* Qp    = ws + 33554432UL;
  u16* KpT   = ws + 100663296UL;
  u16* VhT   = ws + 167772160UL;
  u16* wqkvT = ws + 201326592UL;
  u16* woT   = ws + 204472320UL;
  u16* rfT   = ws + 205520896UL;
  float* partial = (float*)xb;          // [512][128][65] f32, alias xb (dead)
  u16* KVT   = wqkvT;                   // [64][80][128] bf16, alias wqkvT (dead)
  u16* Abuf  = xb;                      // [32768][1024] bf16, alias xb

  cast_x_kernel<<<4096, 256, 0, stream>>>(x, xb, 8388608L);
  transpose_cast_kernel<<<1024, 256, 0, stream>>>(Wq, wqkvT,            1024, 1024);
  transpose_cast_kernel<<<1024, 256, 0, stream>>>(Wk, wqkvT + 1048576,  1024, 1024);
  transpose_cast_kernel<<<1024, 256, 0, stream>>>(Wv, wqkvT + 2097152,  1024, 1024);
  transpose_cast_kernel<<<1024, 256, 0, stream>>>(Wo, woT,              1024, 1024);
  transpose_cast_kernel<<<8,    256, 0, stream>>>(rf, rfT,              64,   128);

  gemm_qkv_phi_kernel<<<6144, 256, 0, stream>>>(xb, wqkvT, rfT, Qp, KpT, VhT);
  kv_partial_kernel<<<512, 256, 0, stream>>>(KpT, VhT, partial);
  kv_reduce_kernel<<<64, 256, 0, stream>>>(partial, KVT);
  qkv_div_kernel<<<4096, 256, 0, stream>>>(Qp, KVT, Abuf);
  gemm_out_kernel<<<2048, 256, 0, stream>>>(Abuf, woT, out);
}

// Round 4
// 561.659 us; speedup vs baseline: 2.3961x; 1.5570x over previous
//
#include <hip/hip_runtime.h>
#include <stdint.h>

// LinearSelfAttention: out = ((phi(xWq) @ (phi(xWk)^T V)) / Z) @ Wo
// B=4 S=8192 H=16 Dh=64 F=128 Dm=1024. All GEMMs bf16-MFMA/fp32-acc.
// R4: main-loop LDS swizzle (pre-swizzled gload_lds source + swizzled read),
//     VGPR<=170 (hh-seq phi, launch_bounds(256,3)) -> 3 waves/SIMD,
//     bijective XCD block swizzle on both big GEMMs.

#define DEVINL __device__ __forceinline__

typedef float f32x4 __attribute__((ext_vector_type(4)));
typedef __bf16 bf16x8 __attribute__((ext_vector_type(8)));
typedef unsigned short u16;

#define TSTR 136   // epilogue tile row stride (u16): 272B, 16B-aligned
#define RSTR 72    // rf row stride (u16): 144B, 16B-aligned

DEVINL u16 f2bf(float f) {
  union { float f; uint32_t u; } v; v.f = f;
  uint32_t u = v.u;
  u += 0x7fffu + ((u >> 16) & 1u);   // round-to-nearest-even
  return (u16)(u >> 16);
}
DEVINL float bf2f(u16 h) {
  union { uint32_t u; float f; } v; v.u = ((uint32_t)h) << 16;
  return v.f;
}

#define GLOAD16(gp, lp) __builtin_amdgcn_global_load_lds( \
    (const __attribute__((address_space(1))) unsigned int*)(gp), \
    (__attribute__((address_space(3))) unsigned int*)(lp), 16, 0, 0)

// ---- linear staging (kv_partial / qkv_div keep this) ----
template <int ROWS>
DEVINL void stage_r128(const uint8_t* g, size_t stride, u16* lds, int wave, int lane) {
#pragma unroll
  for (int j = 0; j < ROWS / 32; ++j) {
    int row = wave * (ROWS / 4) + j * 8 + (lane >> 3);
    GLOAD16(g + (size_t)row * stride + (size_t)(lane & 7) * 16,
            (uint8_t*)lds + (size_t)(wave * (ROWS / 4) + j * 8) * 128);
  }
}

template <int ROWS>
DEVINL void stage_r256(const uint8_t* g, size_t stride, u16* lds, int wave, int lane) {
#pragma unroll
  for (int j = 0; j < ROWS / 16; ++j) {
    int row = wave * (ROWS / 4) + j * 4 + (lane >> 4);
    GLOAD16(g + (size_t)row * stride + (size_t)(lane & 15) * 16,
            (uint8_t*)lds + (size_t)(wave * (ROWS / 4) + j * 4) * 256);
  }
}

// ---- swizzled staging: LDS[row][c] holds global[row][c ^ (row&7)] ----
// (rule #21: linear gload_lds dest + inverse-swizzled per-lane SOURCE)
DEVINL void stage128_sw(const uint8_t* g, size_t stride, u16* lds, int wave, int lane) {
  const int c = (lane & 7) ^ (lane >> 3);   // row&7 == lane>>3
#pragma unroll
  for (int j = 0; j < 4; ++j) {
    int row = wave * 32 + j * 8 + (lane >> 3);
    GLOAD16(g + (size_t)row * stride + (size_t)c * 16,
            (uint8_t*)lds + (size_t)(wave * 32 + j * 8) * 128);
  }
}

// 128x128 tile, BK=64, 4 waves 2x2, 4x4 frags; SWIZZLED LDS reads.
DEVINL void mma128_sw(const u16* As, const u16* Bs, f32x4 acc[4][4],
                      int wr, int wc, int lane) {
#pragma unroll
  for (int kk = 0; kk < 2; ++kk) {
    const int cw = kk * 4 + (lane >> 4);     // 16B-chunk index 0..7
    const int sw = (cw ^ (lane & 7)) * 8;    // row&7 == lane&7 for frag rows
    bf16x8 a[4], b[4];
#pragma unroll
    for (int m = 0; m < 4; ++m)
      a[m] = *(const bf16x8*)&As[(size_t)(wr * 64 + m * 16 + (lane & 15)) * 64 + sw];
#pragma unroll
    for (int n = 0; n < 4; ++n)
      b[n] = *(const bf16x8*)&Bs[(size_t)(wc * 64 + n * 16 + (lane & 15)) * 64 + sw];
#pragma unroll
    for (int m = 0; m < 4; ++m)
#pragma unroll
      for (int n = 0; n < 4; ++n)
        acc[m][n] = __builtin_amdgcn_mfma_f32_16x16x32_bf16(a[m], b[n], acc[m][n], 0, 0, 0);
  }
}

// ---------------- prep kernels ----------------

__global__ __launch_bounds__(256) void cast_x_kernel(
    const float* __restrict__ src, u16* __restrict__ dst, long n4) {
  long i = (long)blockIdx.x * 256 + threadIdx.x;
  const long stride = (long)gridDim.x * 256;
  const float4* s4 = (const float4*)src;
  uint2* d4 = (uint2*)dst;
  for (; i < n4; i += stride) {
    float4 v = s4[i];
    uint2 o;
    o.x = (uint32_t)f2bf(v.x) | ((uint32_t)f2bf(v.y) << 16);
    o.y = (uint32_t)f2bf(v.z) | ((uint32_t)f2bf(v.w) << 16);
    d4[i] = o;
  }
}

// src fp32 [R][C] -> dst bf16 [C][R]
__global__ __launch_bounds__(256) void transpose_cast_kernel(
    const float* __restrict__ src, u16* __restrict__ dst, int R, int C) {
  __shared__ float tile[32 * 33];
  const int ntr = R >> 5;
  const int tr = blockIdx.x % ntr, tc = blockIdx.x / ntr;
  const int tid = threadIdx.x;
  {
    int r = tid >> 3, c4 = (tid & 7) * 4;
    float4 v = *(const float4*)&src[(size_t)(tr * 32 + r) * C + tc * 32 + c4];
    tile[r * 33 + c4 + 0] = v.x;
    tile[r * 33 + c4 + 1] = v.y;
    tile[r * 33 + c4 + 2] = v.z;
    tile[r * 33 + c4 + 3] = v.w;
  }
  __syncthreads();
  {
    int c = tid >> 3, r4 = (tid & 7) * 4;
    uint2 o;
    o.x = (uint32_t)f2bf(tile[(r4 + 0) * 33 + c]) |
          ((uint32_t)f2bf(tile[(r4 + 1) * 33 + c]) << 16);
    o.y = (uint32_t)f2bf(tile[(r4 + 2) * 33 + c]) |
          ((uint32_t)f2bf(tile[(r4 + 3) * 33 + c]) << 16);
    *(uint2*)&dst[(size_t)(tc * 32 + c) * R + tr * 32 + r4] = o;
  }
}

// ---------------- QKV GEMM (N = 3 x 1024) + fused phi ----------------
__global__ __launch_bounds__(256, 3) void gemm_qkv_phi_kernel(
    const u16* __restrict__ xb, const u16* __restrict__ wT,
    const u16* __restrict__ rfT,
    u16* __restrict__ Qp, u16* __restrict__ KpT, u16* __restrict__ VhT) {
  __shared__ u16 smem[26624];               // 52 KiB
  u16* As = smem;                           // [128][64] swizzled
  u16* Bs = smem + 8192;                    // [128][64] swizzled
  u16* Rs = smem + 17408;                   // [128 f][RSTR] (epilogue only)
  const int tid = threadIdx.x, lane = tid & 63, wave = tid >> 6;
  const int wr = wave >> 1, wc = wave & 1;
  // bijective XCD swizzle: 6144 = 8 * 768; same-tm blocks share an XCD L2
  const int nb = (blockIdx.x & 7) * 768 + (blockIdx.x >> 3);
  const int tn = nb % 24, tm = nb / 24;
  const int tensor = tn >> 3;

  f32x4 acc[4][4];
#pragma unroll
  for (int m = 0; m < 4; ++m)
#pragma unroll
    for (int n = 0; n < 4; ++n) acc[m][n] = (f32x4){0.f, 0.f, 0.f, 0.f};

  const uint8_t* aB = (const uint8_t*)(xb + (size_t)tm * 128 * 1024);
  const uint8_t* bB = (const uint8_t*)(wT + (size_t)tn * 128 * 1024);
  for (int kt = 0; kt < 16; ++kt) {
    stage128_sw(aB + kt * 128, 2048, As, wave, lane);
    stage128_sw(bB + kt * 128, 2048, Bs, wave, lane);
    __syncthreads();
    mma128_sw(As, Bs, acc, wr, wc, lane);
    __syncthreads();
  }

  const int b = (tm * 128) >> 13;
  const int sblk = (tm * 128) & 8191;

  if (tensor == 2) {
    // V: transpose 128x128 tile via padded LDS, coalesced 16B rows out.
#pragma unroll
    for (int m = 0; m < 4; ++m) {
      int sl = wr * 64 + m * 16 + (lane >> 4) * 4;
#pragma unroll
      for (int n = 0; n < 4; ++n) {
        int cl = wc * 64 + n * 16 + (lane & 15);
#pragma unroll
        for (int r = 0; r < 4; ++r) smem[cl * TSTR + sl + r] = f2bf(acc[m][n][r]);
      }
    }
    __syncthreads();
#pragma unroll
    for (int it = 0; it < 8; ++it) {
      int cl = it * 16 + (tid >> 4);
      int c = (tn & 7) * 128 + cl;
      int h = c >> 6, d = c & 63;
      size_t off = ((size_t)((b * 16 + h) * 64 + d)) * 8192 + sblk + (tid & 15) * 8;
      *(uint4*)&VhT[off] = *(const uint4*)&smem[cl * TSTR + (tid & 15) * 8];
    }
    return;
  }

  // ---- Q/K: fused phi ----
  // 1) dump bf16 GEMM tile into TILE [128 s][TSTR]
#pragma unroll
  for (int m = 0; m < 4; ++m) {
    int sl = wr * 64 + m * 16 + (lane >> 4) * 4;
#pragma unroll
    for (int n = 0; n < 4; ++n) {
      int cl = wc * 64 + n * 16 + (lane & 15);
#pragma unroll
      for (int r = 0; r < 4; ++r) smem[(sl + r) * TSTR + cl] = f2bf(acc[m][n][r]);
    }
  }
  // 2) load rf into padded Rs (L2-hot after first blocks)
#pragma unroll
  for (int p4 = 0; p4 < 4; ++p4) {
    int idx = p4 * 256 + tid;
    int f = idx >> 3, c = idx & 7;
    *(uint4*)&Rs[f * RSTR + c * 8] = *(const uint4*)&rfT[f * 64 + c * 8];
  }
  __syncthreads();

  // 3) preload a-frags for BOTH heads (TILE becomes reusable after)
  bf16x8 afr[2][2][2];   // [hh][kk][m]
#pragma unroll
  for (int hh = 0; hh < 2; ++hh)
#pragma unroll
    for (int kk = 0; kk < 2; ++kk) {
      const int ko = kk * 32 + (lane >> 4) * 8;
#pragma unroll
      for (int m = 0; m < 2; ++m)
        afr[hh][kk][m] = *(const bf16x8*)&smem[
            (size_t)(wave * 32 + m * 16 + (lane & 15)) * TSTR + hh * 64 + ko];
    }
  __syncthreads();

  const float SC = 0.088388347648318447f;  // 128^-0.5
#pragma unroll
  for (int hh = 0; hh < 2; ++hh) {
    const int h = (tn & 7) * 2 + hh;
    f32x4 p[2][8];
#pragma unroll
    for (int m = 0; m < 2; ++m)
#pragma unroll
      for (int n = 0; n < 8; ++n) p[m][n] = (f32x4){0.f, 0.f, 0.f, 0.f};
#pragma unroll
    for (int kk = 0; kk < 2; ++kk) {
      const int ko = kk * 32 + (lane >> 4) * 8;
      bf16x8 bb[8];
#pragma unroll
      for (int n = 0; n < 8; ++n)
        bb[n] = *(const bf16x8*)&Rs[(size_t)(n * 16 + (lane & 15)) * RSTR + ko];
#pragma unroll
      for (int m = 0; m < 2; ++m)
#pragma unroll
        for (int n = 0; n < 8; ++n)
          p[m][n] = __builtin_amdgcn_mfma_f32_16x16x32_bf16(afr[hh][kk][m], bb[n], p[m][n], 0, 0, 0);
    }

    if (tensor == 0) {
      // Q: phi -> TILE [s][TSTR] -> coalesced row stores
#pragma unroll
      for (int m = 0; m < 2; ++m)
#pragma unroll
        for (int n = 0; n < 8; ++n) {
          int f = n * 16 + (lane & 15);
          int sl = wave * 32 + m * 16 + (lane >> 4) * 4;
#pragma unroll
          for (int r = 0; r < 4; ++r) {
            float v = ((n < 4) ? __cosf(p[m][n][r]) : __sinf(p[m][n][r])) * SC;
            smem[(sl + r) * TSTR + f] = f2bf(v);
          }
        }
      __syncthreads();
      const size_t base_bh = (size_t)(b * 16 + h) * 8192;
#pragma unroll
      for (int it = 0; it < 8; ++it) {
        int s = it * 16 + (tid >> 4);
        *(uint4*)&Qp[(base_bh + sblk + s) * 128 + (tid & 15) * 8] =
            *(const uint4*)&smem[s * TSTR + (tid & 15) * 8];
      }
    } else {
      // K: phi transposed -> TILE [f][TSTR] -> coalesced s-row stores
#pragma unroll
      for (int m = 0; m < 2; ++m)
#pragma unroll
        for (int n = 0; n < 8; ++n) {
          int f = n * 16 + (lane & 15);
          int sl = wave * 32 + m * 16 + (lane >> 4) * 4;
#pragma unroll
          for (int r = 0; r < 4; ++r) {
            float v = ((n < 4) ? __cosf(p[m][n][r]) : __sinf(p[m][n][r])) * SC;
            smem[f * TSTR + sl + r] = f2bf(v);
          }
        }
      __syncthreads();
#pragma unroll
      for (int it = 0; it < 8; ++it) {
        int f = it * 16 + (tid >> 4);
        *(uint4*)&KpT[((size_t)(b * 16 + h) * 128 + f) * 8192 + sblk + (tid & 15) * 8] =
            *(const uint4*)&smem[f * TSTR + (tid & 15) * 8];
      }
    }
    if (hh == 0) __syncthreads();   // stores done before overwriting TILE
  }
}

// ---------------- KV = Kp^T V + Ksum, partial over s-chunks ----------------
__global__ __launch_bounds__(256) void kv_partial_kernel(
    const u16* __restrict__ KpT, const u16* __restrict__ VhT,
    float* __restrict__ partial) {
  __shared__ u16 smem[12288];
  __shared__ float ksmem[256];
  u16* As = smem;        // [128 f][64 s]
  u16* Bs = smem + 8192; // [64 d][64 s]
  const int tid = threadIdx.x, lane = tid & 63, wave = tid >> 6;
  const int bh = blockIdx.x >> 3, ch = blockIdx.x & 7;
  const uint8_t* aB = (const uint8_t*)(KpT + (size_t)bh * 128 * 8192 + ch * 1024);
  const uint8_t* bB = (const uint8_t*)(VhT + (size_t)bh * 64 * 8192 + ch * 1024);

  f32x4 acc[2][4];
#pragma unroll
  for (int m = 0; m < 2; ++m)
#pragma unroll
    for (int n = 0; n < 4; ++n) acc[m][n] = (f32x4){0.f, 0.f, 0.f, 0.f};
  float ks = 0.f;
  const int fK = tid >> 1, sO = (tid & 1) * 32;

  for (int t = 0; t < 16; ++t) {
    stage_r128<128>(aB + t * 128, 16384, As, wave, lane);
    stage_r128<64>(bB + t * 128, 16384, Bs, wave, lane);
    __syncthreads();
#pragma unroll
    for (int i = 0; i < 4; ++i) {
      uint4 v = *(const uint4*)&As[fK * 64 + sO + i * 8];
      ks += bf2f((u16)(v.x & 0xffff)) + bf2f((u16)(v.x >> 16));
      ks += bf2f((u16)(v.y & 0xffff)) + bf2f((u16)(v.y >> 16));
      ks += bf2f((u16)(v.z & 0xffff)) + bf2f((u16)(v.z >> 16));
      ks += bf2f((u16)(v.w & 0xffff)) + bf2f((u16)(v.w >> 16));
    }
#pragma unroll
    for (int kk = 0; kk < 2; ++kk) {
      const int ko = kk * 32 + (lane >> 4) * 8;
      bf16x8 a[2], bb[4];
#pragma unroll
      for (int m = 0; m < 2; ++m)
        a[m] = *(const bf16x8*)&As[(size_t)(wave * 32 + m * 16 + (lane & 15)) * 64 + ko];
#pragma unroll
      for (int n = 0; n < 4; ++n)
        bb[n] = *(const bf16x8*)&Bs[(size_t)(n * 16 + (lane & 15)) * 64 + ko];
#pragma unroll
      for (int m = 0; m < 2; ++m)
#pragma unroll
        for (int n = 0; n < 4; ++n)
          acc[m][n] = __builtin_amdgcn_mfma_f32_16x16x32_bf16(a[m], bb[n], acc[m][n], 0, 0, 0);
    }
    __syncthreads();
  }

  float* pb = partial + (size_t)blockIdx.x * (128 * 65);
#pragma unroll
  for (int m = 0; m < 2; ++m)
#pragma unroll
    for (int n = 0; n < 4; ++n) {
      int d = n * 16 + (lane & 15);
#pragma unroll
      for (int r = 0; r < 4; ++r) {
        int f = wave * 32 + m * 16 + (lane >> 4) * 4 + r;
        pb[f * 65 + d] = acc[m][n][r];
      }
    }
  ksmem[tid] = ks;
  __syncthreads();
  if (tid < 128) pb[tid * 65 + 64] = ksmem[2 * tid] + ksmem[2 * tid + 1];
}

// reduce partials -> KVT [bh][80 rows][128 f] bf16 (row 64 = Ksum, 65..79 = 0)
__global__ __launch_bounds__(256) void kv_reduce_kernel(
    const float* __restrict__ partial, u16* __restrict__ KVT) {
  const int bh = blockIdx.x, tid = threadIdx.x;
  for (int e = tid; e < 8320; e += 256) {
    float s = 0.f;
#pragma unroll
    for (int c = 0; c < 8; ++c) s += partial[(size_t)(bh * 8 + c) * 8320 + e];
    int f = e / 65, col = e % 65;
    KVT[((size_t)bh * 80 + col) * 128 + f] = f2bf(s);
  }
  for (int i = tid; i < 15 * 128; i += 256)
    KVT[((size_t)bh * 80 + 65) * 128 + i] = 0;
}

// ---------------- QKV = Qp @ KV, Z via 5th N-frag, divide -> A bf16 ----------------
__global__ __launch_bounds__(256) void qkv_div_kernel(
    const u16* __restrict__ Qp, const u16* __restrict__ KVT, u16* __restrict__ A) {
  __shared__ u16 smem[26624];
  u16* Qs = smem;          // [128 s][128 f]
  u16* Ks = smem + 16384;  // [80 rows][128 f]
  const int tid = threadIdx.x, lane = tid & 63, wave = tid >> 6;
  const int bh = blockIdx.x >> 6, st = blockIdx.x & 63;

  stage_r256<128>((const uint8_t*)(Qp + ((size_t)bh * 8192 + st * 128) * 128), 256,
                  Qs, wave, lane);
  stage_r256<80>((const uint8_t*)(KVT + (size_t)bh * 80 * 128), 256, Ks, wave, lane);
  __syncthreads();

  f32x4 acc[2][5];
#pragma unroll
  for (int m = 0; m < 2; ++m)
#pragma unroll
    for (int n = 0; n < 5; ++n) acc[m][n] = (f32x4){0.f, 0.f, 0.f, 0.f};

#pragma unroll
  for (int kk = 0; kk < 4; ++kk) {
    const int ko = kk * 32 + (lane >> 4) * 8;
    bf16x8 a[2], bb[5];
#pragma unroll
    for (int m = 0; m < 2; ++m)
      a[m] = *(const bf16x8*)&Qs[(size_t)(wave * 32 + m * 16 + (lane & 15)) * 128 + ko];
#pragma unroll
    for (int n = 0; n < 5; ++n)
      bb[n] = *(const bf16x8*)&Ks[(size_t)(n * 16 + (lane & 15)) * 128 + ko];
#pragma unroll
    for (int m = 0; m < 2; ++m)
#pragma unroll
      for (int n = 0; n < 5; ++n)
        acc[m][n] = __builtin_amdgcn_mfma_f32_16x16x32_bf16(a[m], bb[n], acc[m][n], 0, 0, 0);
  }

  const int b_ = bh >> 4, h = bh & 15;
#pragma unroll
  for (int m = 0; m < 2; ++m) {
#pragma unroll
    for (int r = 0; r < 4; ++r) {
      float z = fmaxf(__shfl(acc[m][4][r], lane & 48), 1e-6f);
      int srow = st * 128 + wave * 32 + m * 16 + (lane >> 4) * 4 + r;
      size_t rowb = ((size_t)b_ * 8192 + srow) * 1024 + h * 64;
#pragma unroll
      for (int n = 0; n < 4; ++n)
        A[rowb + n * 16 + (lane & 15)] = f2bf(acc[m][n][r] / z);
    }
  }
}

// ---------------- out = A @ Wo (fp32 out) ----------------
__global__ __launch_bounds__(256, 3) void gemm_out_kernel(
    const u16* __restrict__ A, const u16* __restrict__ WoT, float* __restrict__ out) {
  __shared__ u16 smem[16384];
  u16* As = smem;
  u16* Bs = smem + 8192;
  const int tid = threadIdx.x, lane = tid & 63, wave = tid >> 6;
  const int wr = wave >> 1, wc = wave & 1;
  // bijective XCD swizzle: 2048 = 8 * 256
  const int nb = (blockIdx.x & 7) * 256 + (blockIdx.x >> 3);
  const int tn = nb & 7, tm = nb >> 3;

  f32x4 acc[4][4];
#pragma unroll
  for (int m = 0; m < 4; ++m)
#pragma unroll
    for (int n = 0; n < 4; ++n) acc[m][n] = (f32x4){0.f, 0.f, 0.f, 0.f};

  const uint8_t* aB = (const uint8_t*)(A + (size_t)tm * 128 * 1024);
  const uint8_t* bB = (const uint8_t*)(WoT + (size_t)tn * 128 * 1024);
  for (int kt = 0; kt < 16; ++kt) {
    stage128_sw(aB + kt * 128, 2048, As, wave, lane);
    stage128_sw(bB + kt * 128, 2048, Bs, wave, lane);
    __syncthreads();
    mma128_sw(As, Bs, acc, wr, wc, lane);
    __syncthreads();
  }

  const int rowbase = tm * 128 + wr * 64;
  const int colbase = tn * 128 + wc * 64;
#pragma unroll
  for (int m = 0; m < 4; ++m)
#pragma unroll
    for (int n = 0; n < 4; ++n) {
      int col = colbase + n * 16 + (lane & 15);
      int row = rowbase + m * 16 + (lane >> 4) * 4;
#pragma unroll
      for (int r = 0; r < 4; ++r)
        out[(size_t)(row + r) * 1024 + col] = acc[m][n][r];
    }
}

// ---------------- host ----------------

extern "C" void kernel_launch(void* const* d_in, const int* in_sizes, int n_in,
                              void* d_out, int out_size, void* d_ws, size_t ws_size,
                              hipStream_t stream) {
  const float* x  = (const float*)d_in[0];
  const float* Wq = (const float*)d_in[1];
  const float* Wk = (const float*)d_in[2];
  const float* Wv = (const float*)d_in[3];
  const float* Wo = (const float*)d_in[4];
  const float* rf = (const float*)d_in[5];
  float* out = (float*)d_out;

  if (ws_size < (size_t)411058176) return;   // fail cleanly, don't fault

  u16* ws = (u16*)d_ws;
  u16* xb    = ws;
  u16* Qp    = ws + 33554432UL;
  u16* KpT   = ws + 100663296UL;
  u16* VhT   = ws + 167772160UL;
  u16* wqkvT = ws + 201326592UL;
  u16* woT   = ws + 204472320UL;
  u16* rfT   = ws + 205520896UL;
  float* partial = (float*)xb;          // [512][128][65] f32, alias xb (dead)
  u16* KVT   = wqkvT;                   // [64][80][128] bf16, alias wqkvT (dead)
  u16* Abuf  = xb;                      // [32768][1024] bf16, alias xb

  cast_x_kernel<<<4096, 256, 0, stream>>>(x, xb, 8388608L);
  transpose_cast_kernel<<<1024, 256, 0, stream>>>(Wq, wqkvT,            1024, 1024);
  transpose_cast_kernel<<<1024, 256, 0, stream>>>(Wk, wqkvT + 1048576,  1024, 1024);
  transpose_cast_kernel<<<1024, 256, 0, stream>>>(Wv, wqkvT + 2097152,  1024, 1024);
  transpose_cast_kernel<<<1024, 256, 0, stream>>>(Wo, woT,              1024, 1024);
  transpose_cast_kernel<<<8,    256, 0, stream>>>(rf, rfT,              64,   128);

  gemm_qkv_phi_kernel<<<6144, 256, 0, stream>>>(xb, wqkvT, rfT, Qp, KpT, VhT);
  kv_partial_kernel<<<512, 256, 0, stream>>>(KpT, VhT, partial);
  kv_reduce_kernel<<<64, 256, 0, stream>>>(partial, KVT);
  qkv_div_kernel<<<4096, 256, 0, stream>>>(Qp, KVT, Abuf);
  gemm_out_kernel<<<2048, 256, 0, stream>>>(Abuf, woT, out);
}